// Round 12
// baseline (23.823 us; speedup 1.0000x reference)
//
#include <hip/hip_runtime.h>
#include <math.h>

#define NB 8
#define N_OP 1000
#define N_MA 64
#define IN_DST 64
#define DD 128
#define NEG_SLOPE 0.2f
#define TILE_O 32
#define NTILE 32   // 32*32 = 1024 >= 1000 (tail guarded)
#define HPAD 132   // H tile stride: breaks bank aliasing on the el reduce

__device__ __forceinline__ float lrelu(float x) { return x >= 0.f ? x : NEG_SLOPE * x; }

__device__ __forceinline__ float wave_sum(float v) {
    for (int off = 32; off; off >>= 1) v += __shfl_xor(v, off, 64);
    return v;
}

// K1: per (b, o-tile), 512 threads. Self-contained: cheap 8-wave in-block
// prep (c_we, u, v, er — 4-8 threads/output, L1-line-friendly direct reads),
// el from staged H, masked exp stats (M=0; logits bounded ~14, safe f32),
// partial contraction S_part[b,ti,m,i] = sum_o p[o,m]*H[o,i].
__global__ __launch_bounds__(512) void ab4_kernel(
    const float* __restrict__ h_src, const float* __restrict__ h_dst,
    const float* __restrict__ edge_feat, const int* __restrict__ adj,
    const float* __restrict__ W_src, const float* __restrict__ W_dst,
    const float* __restrict__ W_edge, const float* __restrict__ attn_l,
    const float* __restrict__ attn_r, float* __restrict__ S_part,
    float* __restrict__ zpart, float* __restrict__ separt) {
    __shared__ float H_l[TILE_O][HPAD];    // 16.9 KB
    __shared__ float P_l[TILE_O][N_MA];    // 8 KB
    __shared__ float u_l[DD];
    __shared__ float v_l[IN_DST];
    __shared__ float er_l[N_MA];
    __shared__ float el_l[TILE_O];
    __shared__ float redz[8][64], redse[8][64];  // 4 KB

    int blk = blockIdx.x;               // 0..255
    int b = blk >> 5, ti = blk & 31;
    int o0 = ti * TILE_O;
    int nrows = min(TILE_O, N_OP - o0); // 32 (8 for ti==31)
    int t = threadIdx.x;                // 0..511
    int lane = t & 63;

    // stage H tile (coalesced float4); zero OOB rows — loads issued first
    #pragma unroll
    for (int c = 0; c < 2; ++c) {
        int flat = c * 512 + t;          // 1024 float4 slots = 32 rows x 32
        int row = flat >> 5, col = (flat & 31) * 4;
        float4 hv = make_float4(0.f, 0.f, 0.f, 0.f);
        if (row < nrows)
            hv = *reinterpret_cast<const float4*>(
                h_src + ((size_t)(b * N_OP + o0 + row) * DD + col));
        *reinterpret_cast<float4*>(&H_l[row][col]) = hv;
    }

    // c_we = dot(W_edge, attn_l): wave-redundant (coalesced reads + wave_sum)
    float cwe = wave_sum(W_edge[lane] * attn_l[lane] +
                         W_edge[lane + 64] * attn_l[lane + 64]);

    // u[i] = dot(W_src[i,:], attn_l): 4 threads/row x 32 FMA
    {
        int i = t >> 2, q4 = t & 3;
        const float* wr = W_src + i * DD + q4 * 32;
        const float* al = attn_l + q4 * 32;
        float part = 0.f;
        #pragma unroll 8
        for (int q = 0; q < 32; ++q) part += wr[q] * al[q];
        part += __shfl_xor(part, 1, 64);
        part += __shfl_xor(part, 2, 64);
        if (q4 == 0) u_l[i] = part;
    }
    // v[k] = dot(W_dst[k,:], attn_r): 8 threads/row x 16 FMA
    {
        int k = t >> 3, s8 = t & 7;
        const float* wd = W_dst + k * DD + s8 * 16;
        const float* ar = attn_r + s8 * 16;
        float part = 0.f;
        #pragma unroll
        for (int q = 0; q < 16; ++q) part += wd[q] * ar[q];
        part += __shfl_xor(part, 1, 64);
        part += __shfl_xor(part, 2, 64);
        part += __shfl_xor(part, 4, 64);
        if (s8 == 0) v_l[k] = part;
    }
    __syncthreads();  // H_l, u_l, v_l ready

    // er[m] = dot(h_dst[b,m,:], v): 8 threads/m x 8 FMA
    {
        int m = t >> 3, s8 = t & 7;
        const float* hd = h_dst + (size_t)(b * N_MA + m) * IN_DST + s8 * 8;
        float part = 0.f;
        #pragma unroll
        for (int q = 0; q < 8; ++q) part += hd[q] * v_l[s8 * 8 + q];
        part += __shfl_xor(part, 1, 64);
        part += __shfl_xor(part, 2, 64);
        part += __shfl_xor(part, 4, 64);
        if (s8 == 0) er_l[m] = part;
    }
    // el[r] = dot(H[r,:], u): 16 threads/row x 8 FMA (OOB rows give 0)
    {
        int r = t >> 4, s16 = t & 15;
        float part = 0.f;
        #pragma unroll
        for (int q = 0; q < 8; ++q)
            part += H_l[r][s16 + 16 * q] * u_l[s16 + 16 * q];
        part += __shfl_xor(part, 1, 64);
        part += __shfl_xor(part, 2, 64);
        part += __shfl_xor(part, 4, 64);
        part += __shfl_xor(part, 8, 64);
        if (s16 == 0) el_l[r] = part;
    }
    __syncthreads();  // er_l, el_l ready

    // phase 1: p + per-tile stats (coalesced adj/ef rows); 8 row-groups
    int m = t & 63, og = t >> 6;        // og in [0,8)
    float er_bm = er_l[m];
    float z = 0.f, se = 0.f;
    #pragma unroll
    for (int r = og; r < TILE_O; r += 8) {
        float p = 0.f;
        if (r < nrows) {
            size_t eidx = (size_t)(b * N_OP + o0 + r) * N_MA + m;
            if (adj[eidx]) {
                float efv = edge_feat[eidx];
                float v = lrelu(el_l[r] + er_bm + efv * cwe);
                p = __expf(v);
                z += p;
                se += p * efv;
            }
        }
        P_l[r][m] = p;
    }
    redz[og][m] = z;
    redse[og][m] = se;
    __syncthreads();

    if (t < 64) {
        float s = 0.f;
        #pragma unroll
        for (int g = 0; g < 8; ++g) s += redz[g][t];
        zpart[ti * 512 + b * N_MA + t] = s;
    } else if (t < 128) {
        int mm = t - 64;
        float s = 0.f;
        #pragma unroll
        for (int g = 0; g < 8; ++g) s += redse[g][mm];
        separt[ti * 512 + b * N_MA + mm] = s;
    }

    // phase 2: S_part[m][i] = sum_k P_l[k][m] * H_l[k][i]
    int i4 = t & 31, mg = t >> 5;       // mg in [0,16)
    float acc[4][4];
    #pragma unroll
    for (int a = 0; a < 4; ++a)
        #pragma unroll
        for (int c = 0; c < 4; ++c) acc[a][c] = 0.f;

    for (int k = 0; k < TILE_O; ++k) {
        float4 hv = *reinterpret_cast<const float4*>(&H_l[k][i4 * 4]);
        float4 pa = *reinterpret_cast<const float4*>(&P_l[k][mg * 4]);
        float hh[4] = {hv.x, hv.y, hv.z, hv.w};
        float pp[4] = {pa.x, pa.y, pa.z, pa.w};
        #pragma unroll
        for (int mm = 0; mm < 4; ++mm)
            #pragma unroll
            for (int ii = 0; ii < 4; ++ii)
                acc[mm][ii] += pp[mm] * hh[ii];
    }

    #pragma unroll
    for (int mm = 0; mm < 4; ++mm) {
        size_t off = ((size_t)(b * NTILE + ti) * N_MA + mg * 4 + mm) * DD + i4 * 4;
        *reinterpret_cast<float4*>(S_part + off) =
            make_float4(acc[mm][0], acc[mm][1], acc[mm][2], acc[mm][3]);
    }
}

// K2: per (b,m), 512 threads: sum tile partials (4 groups); recompute
// feat_dst row + er in-block (coalesced W_dst columns); W_src matvec;
// sigmoid epilogue.
__global__ __launch_bounds__(512) void c2_kernel(
    const float* __restrict__ S_part, const float* __restrict__ zpart,
    const float* __restrict__ separt, const float* __restrict__ h_dst,
    const float* __restrict__ W_dst, const float* __restrict__ W_src,
    const float* __restrict__ W_edge, const float* __restrict__ attn_r,
    float* __restrict__ out) {
    __shared__ float Sp[4][DD];
    __shared__ float Fp[4][DD];
    __shared__ float Wp[4][DD];
    __shared__ float S_l[DD];
    __shared__ float fd_l[DD];
    __shared__ float hd_l[IN_DST];
    __shared__ float sZ, sSE, sER;

    int bm = blockIdx.x;
    int t = threadIdx.x;                // 0..511
    int lane = t & 63, w = t >> 6;      // w in [0,8)
    int i = t & 127, h = t >> 7;        // h in [0,4)

    // region A: hd_l, stats, Sp
    if (t < IN_DST) hd_l[t] = h_dst[(size_t)bm * IN_DST + t];

    if (w == 0) {
        float vz = (lane < NTILE) ? zpart[lane * 512 + bm] : 0.f;
        vz = wave_sum(vz);
        if (lane == 0) sZ = vz;
    } else if (w == 1) {
        float vs = (lane < NTILE) ? separt[lane * 512 + bm] : 0.f;
        vs = wave_sum(vs);
        if (lane == 0) sSE = vs;
    }

    float ps = 0.f;
    #pragma unroll
    for (int q = 0; q < NTILE / 4; ++q) {
        int ti = h * (NTILE / 4) + q;
        ps += S_part[((size_t)((bm >> 6) * NTILE + ti) * N_MA + (bm & 63)) * DD + i];
    }
    Sp[h][i] = ps;
    __syncthreads();

    // region B: S_l, Fp
    if (t < DD) S_l[t] = Sp[0][t] + Sp[1][t] + Sp[2][t] + Sp[3][t];
    float fa = 0.f;
    #pragma unroll
    for (int k = h * 16; k < h * 16 + 16; ++k) fa += hd_l[k] * W_dst[k * DD + i];
    Fp[h][i] = fa;
    __syncthreads();

    // region C: fd_l, Wp (needs S_l)
    if (t < DD) fd_l[t] = Fp[0][t] + Fp[1][t] + Fp[2][t] + Fp[3][t];
    float acc = 0.f;
    #pragma unroll 8
    for (int q = 0; q < 32; ++q) {
        int ii = h * 32 + q;
        acc += S_l[ii] * W_src[ii * DD + i];
    }
    Wp[h][i] = acc;
    __syncthreads();

    // region D: sER (needs fd_l)
    if (w == 0) {
        float e = fd_l[lane] * attn_r[lane] + fd_l[lane + 64] * attn_r[lane + 64];
        e = wave_sum(e);
        if (lane == 0) sER = e;
    }
    __syncthreads();

    // region E: epilogue
    if (t < DD) {
        float p_kk = __expf(lrelu(2.f * sER));
        float Z = sZ + p_kk;
        float invZ = 1.f / Z;
        float bsrc = (Wp[0][i] + Wp[1][i] + Wp[2][i] + Wp[3][i]) * invZ;
        float val = W_edge[i] * (sSE * invZ) + bsrc + fd_l[i] * (p_kk * invZ);
        out[(size_t)bm * DD + i] = 1.f / (1.f + __expf(-val));
    }
}

extern "C" void kernel_launch(void* const* d_in, const int* in_sizes, int n_in,
                              void* d_out, int out_size, void* d_ws, size_t ws_size,
                              hipStream_t stream) {
    const float* h_src = (const float*)d_in[0];
    const float* h_dst = (const float*)d_in[1];
    const float* edge_feat = (const float*)d_in[2];
    const int* adj = (const int*)d_in[3];
    const float* W_src = (const float*)d_in[4];
    const float* W_dst = (const float*)d_in[5];
    const float* W_edge = (const float*)d_in[6];
    const float* attn_l = (const float*)d_in[7];
    const float* attn_r = (const float*)d_in[8];
    float* out = (float*)d_out;

    float* ws = (float*)d_ws;
    float* zpart = ws;                 // 32*512 = 16384
    float* separt = ws + 16384;        // 16384
    float* S_part = ws + 32768;        // 8*32*64*128 = 2097152

    ab4_kernel<<<NB * NTILE, 512, 0, stream>>>(
        h_src, h_dst, edge_feat, adj, W_src, W_dst, W_edge, attn_l, attn_r,
        S_part, zpart, separt);
    c2_kernel<<<NB * N_MA, 512, 0, stream>>>(
        S_part, zpart, separt, h_dst, W_dst, W_src, W_edge, attn_r, out);
}

// Round 13
// 23.028 us; speedup vs baseline: 1.0345x; 1.0345x over previous
//
#include <hip/hip_runtime.h>
#include <math.h>

#define NB 8
#define N_OP 1000
#define N_MA 64
#define IN_DST 64
#define DD 128
#define NEG_SLOPE 0.2f
#define TILE_O 32
#define NTILE 32   // 32*32 = 1024 >= 1000 (tail guarded)
#define HPAD 132   // H tile stride: breaks bank aliasing on the el reduce

__device__ __forceinline__ float lrelu(float x) { return x >= 0.f ? x : NEG_SLOPE * x; }

__device__ __forceinline__ float wave_sum(float v) {
    for (int off = 32; off; off >>= 1) v += __shfl_xor(v, off, 64);
    return v;
}

// K1: independent precomputes in one launch. (proven R6/R11 kernel)
// blocks [0,33): u[i] = dot(W_src[i,:], attn_l) (one row/wave), blk32.w0 -> c_we
// blocks [33,161): feat_dst row + er (one bm/wave)
__global__ __launch_bounds__(256) void prep_fdst(
    const float* __restrict__ W_src, const float* __restrict__ W_edge,
    const float* __restrict__ attn_l, const float* __restrict__ h_dst,
    const float* __restrict__ W_dst, const float* __restrict__ attn_r,
    float* __restrict__ u, float* __restrict__ c_we,
    float* __restrict__ feat_dst, float* __restrict__ er) {
    int blk = blockIdx.x;
    int lane = threadIdx.x & 63;
    int w = threadIdx.x >> 6;
    if (blk < 33) {
        int task = blk * 4 + w;
        float al0 = attn_l[lane], al1 = attn_l[lane + 64];
        if (task < 128) {
            float part = W_src[task * DD + lane] * al0 +
                         W_src[task * DD + lane + 64] * al1;
            part = wave_sum(part);
            if (lane == 0) u[task] = part;
        } else if (task == 128) {
            float part = W_edge[lane] * al0 + W_edge[lane + 64] * al1;
            part = wave_sum(part);
            if (lane == 0) c_we[0] = part;
        }
    } else {
        int bm = (blk - 33) * 4 + w;     // < 512
        const float* h = h_dst + (size_t)bm * IN_DST;
        float a0 = 0.f, a1 = 0.f;
        #pragma unroll 8
        for (int k = 0; k < IN_DST; ++k) {
            float hk = h[k];
            a0 += hk * W_dst[k * DD + lane];
            a1 += hk * W_dst[k * DD + lane + 64];
        }
        feat_dst[(size_t)bm * DD + lane] = a0;
        feat_dst[(size_t)bm * DD + lane + 64] = a1;
        float r = a0 * attn_r[lane] + a1 * attn_r[lane + 64];
        r = wave_sum(r);
        if (lane == 0) er[bm] = r;
    }
}

// K2: per (b, o-tile), 512 threads (2 waves/SIMD). (proven R11 kernel)
__global__ __launch_bounds__(512) void ab_kernel(
    const float* __restrict__ edge_feat, const int* __restrict__ adj,
    const float* __restrict__ h_src, const float* __restrict__ u,
    const float* __restrict__ er, const float* __restrict__ c_we_p,
    float* __restrict__ S_part, float* __restrict__ zpart,
    float* __restrict__ separt) {
    __shared__ float H_l[TILE_O][HPAD];    // 16.9 KB
    __shared__ float P_l[TILE_O][N_MA];    // 8 KB
    __shared__ float u_l[DD];
    __shared__ float el_l[TILE_O];
    __shared__ float redz[8][64], redse[8][64];  // 4 KB

    int blk = blockIdx.x;               // 0..255
    int b = blk >> 5, ti = blk & 31;
    int o0 = ti * TILE_O;
    int nrows = min(TILE_O, N_OP - o0); // 32 (8 for ti==31)
    int t = threadIdx.x;                // 0..511

    float cwe = c_we_p[0];

    // stage H tile (coalesced float4); zero OOB rows
    #pragma unroll
    for (int c = 0; c < 2; ++c) {
        int flat = c * 512 + t;          // 1024 float4 slots = 32 rows x 32
        int row = flat >> 5, col = (flat & 31) * 4;
        float4 hv = make_float4(0.f, 0.f, 0.f, 0.f);
        if (row < nrows)
            hv = *reinterpret_cast<const float4*>(
                h_src + ((size_t)(b * N_OP + o0 + row) * DD + col));
        *reinterpret_cast<float4*>(&H_l[row][col]) = hv;
    }
    if (t < DD) u_l[t] = u[t];
    __syncthreads();

    // el[r] = dot(H[r,:], u): 16 threads/row x 8 FMA (OOB rows give 0)
    {
        int r = t >> 4, sub = t & 15;
        float part = 0.f;
        #pragma unroll
        for (int q = 0; q < 8; ++q)
            part += H_l[r][sub + 16 * q] * u_l[sub + 16 * q];
        part += __shfl_xor(part, 1, 64);
        part += __shfl_xor(part, 2, 64);
        part += __shfl_xor(part, 4, 64);
        part += __shfl_xor(part, 8, 64);
        if (sub == 0) el_l[r] = part;
    }
    __syncthreads();

    // phase 1: p + per-tile stats (coalesced adj/ef rows); 8 row-groups
    int m = t & 63, og = t >> 6;        // og in [0,8)
    float er_bm = er[b * N_MA + m];
    float z = 0.f, se = 0.f;
    #pragma unroll
    for (int r = og; r < TILE_O; r += 8) {
        float p = 0.f;
        if (r < nrows) {
            size_t eidx = (size_t)(b * N_OP + o0 + r) * N_MA + m;
            if (adj[eidx]) {
                float efv = edge_feat[eidx];
                float v = lrelu(el_l[r] + er_bm + efv * cwe);
                p = __expf(v);
                z += p;
                se += p * efv;
            }
        }
        P_l[r][m] = p;
    }
    redz[og][m] = z;
    redse[og][m] = se;
    __syncthreads();

    if (t < 64) {
        float s = 0.f;
        #pragma unroll
        for (int g = 0; g < 8; ++g) s += redz[g][t];
        zpart[ti * 512 + b * N_MA + t] = s;
    } else if (t < 128) {
        int mm = t - 64;
        float s = 0.f;
        #pragma unroll
        for (int g = 0; g < 8; ++g) s += redse[g][mm];
        separt[ti * 512 + b * N_MA + mm] = s;
    }

    // phase 2: S_part[m][i] = sum_k P_l[k][m] * H_l[k][i]
    int i4 = t & 31, mg = t >> 5;       // mg in [0,16)
    float acc[4][4];
    #pragma unroll
    for (int a = 0; a < 4; ++a)
        #pragma unroll
        for (int c = 0; c < 4; ++c) acc[a][c] = 0.f;

    for (int k = 0; k < TILE_O; ++k) {
        float4 hv = *reinterpret_cast<const float4*>(&H_l[k][i4 * 4]);
        float4 pa = *reinterpret_cast<const float4*>(&P_l[k][mg * 4]);
        float hh[4] = {hv.x, hv.y, hv.z, hv.w};
        float pp[4] = {pa.x, pa.y, pa.z, pa.w};
        #pragma unroll
        for (int mm = 0; mm < 4; ++mm)
            #pragma unroll
            for (int ii = 0; ii < 4; ++ii)
                acc[mm][ii] += pp[mm] * hh[ii];
    }

    #pragma unroll
    for (int mm = 0; mm < 4; ++mm) {
        size_t off = ((size_t)(b * NTILE + ti) * N_MA + mg * 4 + mm) * DD + i4 * 4;
        *reinterpret_cast<float4*>(S_part + off) =
            make_float4(acc[mm][0], acc[mm][1], acc[mm][2], acc[mm][3]);
    }
}

// K3: per (b,m), 512 threads (2 waves/SIMD): sum partials (4 groups),
// matvec with W_src (32 FMA/thread), epilogue sigmoid.
__global__ __launch_bounds__(512) void c_kernel(
    const float* __restrict__ S_part, const float* __restrict__ zpart,
    const float* __restrict__ separt, const float* __restrict__ er,
    const float* __restrict__ feat_dst, const float* __restrict__ W_src,
    const float* __restrict__ W_edge, float* __restrict__ out) {
    __shared__ float Sp[4][DD];
    __shared__ float S_l[DD];
    __shared__ float Wp[4][DD];
    __shared__ float sZ, sSE;

    int bm = blockIdx.x;
    int b = bm >> 6, m = bm & 63;
    int t = threadIdx.x;                // 0..511
    int i = t & 127, h = t >> 7;        // h in [0,4)
    int lane = t & 63, w = t >> 6;      // w in [0,8)

    if (w == 0) {
        float v = (lane < NTILE) ? zpart[lane * 512 + bm] : 0.f;
        v = wave_sum(v);
        if (lane == 0) sZ = v;
    } else if (w == 1) {
        float v = (lane < NTILE) ? separt[lane * 512 + bm] : 0.f;
        v = wave_sum(v);
        if (lane == 0) sSE = v;
    }

    // partial sums of S over tiles: 4 groups x 8 tiles (coalesced)
    float ps = 0.f;
    #pragma unroll
    for (int q = 0; q < NTILE / 4; ++q) {
        int ti = h * (NTILE / 4) + q;
        ps += S_part[((size_t)(b * NTILE + ti) * N_MA + m) * DD + i];
    }
    Sp[h][i] = ps;
    __syncthreads();
    if (t < DD) S_l[t] = Sp[0][t] + Sp[1][t] + Sp[2][t] + Sp[3][t];
    __syncthreads();

    // matvec: bsrc[d] = sum_i S_l[i] * W_src[i,d]; 4 groups x 32 FMA
    float acc = 0.f;
    #pragma unroll 8
    for (int q = 0; q < 32; ++q) {
        int ii = h * 32 + q;
        acc += S_l[ii] * W_src[ii * DD + i];
    }
    Wp[h][i] = acc;
    __syncthreads();

    if (t < DD) {
        float er_bm = er[bm];
        float p_kk = __expf(lrelu(2.f * er_bm));
        float Z = sZ + p_kk;
        float invZ = 1.f / Z;
        float bsrc = (Wp[0][i] + Wp[1][i] + Wp[2][i] + Wp[3][i]) * invZ;
        float val = W_edge[i] * (sSE * invZ) + bsrc +
                    feat_dst[(size_t)bm * DD + i] * (p_kk * invZ);
        out[(size_t)bm * DD + i] = 1.f / (1.f + __expf(-val));
    }
}

extern "C" void kernel_launch(void* const* d_in, const int* in_sizes, int n_in,
                              void* d_out, int out_size, void* d_ws, size_t ws_size,
                              hipStream_t stream) {
    const float* h_src = (const float*)d_in[0];
    const float* h_dst = (const float*)d_in[1];
    const float* edge_feat = (const float*)d_in[2];
    const int* adj = (const int*)d_in[3];
    const float* W_src = (const float*)d_in[4];
    const float* W_dst = (const float*)d_in[5];
    const float* W_edge = (const float*)d_in[6];
    const float* attn_l = (const float*)d_in[7];
    const float* attn_r = (const float*)d_in[8];
    float* out = (float*)d_out;

    float* ws = (float*)d_ws;
    float* u = ws;                     // 128
    float* c_we = ws + 128;            // 1
    float* er = ws + 8448;             // 512
    float* feat_dst = ws + 9216;       // 65536
    float* zpart = ws + 75008;         // 32*512 = 16384
    float* separt = ws + 91392;        // 16384
    float* S_part = ws + 107776;       // 8*32*64*128 = 2097152

    prep_fdst<<<161, 256, 0, stream>>>(W_src, W_edge, attn_l, h_dst, W_dst,
                                       attn_r, u, c_we, feat_dst, er);
    ab_kernel<<<NB * NTILE, 512, 0, stream>>>(edge_feat, adj, h_src, u, er,
                                              c_we, S_part, zpart, separt);
    c_kernel<<<NB * N_MA, 512, 0, stream>>>(S_part, zpart, separt, er,
                                            feat_dst, W_src, W_edge, out);
}

// Round 14
// 22.951 us; speedup vs baseline: 1.0380x; 1.0034x over previous
//
#include <hip/hip_runtime.h>
#include <math.h>

#define NB 8
#define N_OP 1000
#define N_MA 64
#define IN_DST 64
#define DD 128
#define NEG_SLOPE 0.2f
#define TILE_O 32
#define NTILE 32   // 32*32 = 1024 >= 1000 (tail guarded)
#define HPAD 132   // H tile stride: breaks bank aliasing on the el reduce

__device__ __forceinline__ float lrelu(float x) { return x >= 0.f ? x : NEG_SLOPE * x; }

__device__ __forceinline__ float wave_sum(float v) {
    for (int off = 32; off; off >>= 1) v += __shfl_xor(v, off, 64);
    return v;
}

// K1: independent precomputes in one launch. (proven R6/R11 kernel)
// blocks [0,33): u[i] = dot(W_src[i,:], attn_l) (one row/wave), blk32.w0 -> c_we
// blocks [33,161): feat_dst row + er (one bm/wave)
__global__ __launch_bounds__(256) void prep_fdst(
    const float* __restrict__ W_src, const float* __restrict__ W_edge,
    const float* __restrict__ attn_l, const float* __restrict__ h_dst,
    const float* __restrict__ W_dst, const float* __restrict__ attn_r,
    float* __restrict__ u, float* __restrict__ c_we,
    float* __restrict__ feat_dst, float* __restrict__ er) {
    int blk = blockIdx.x;
    int lane = threadIdx.x & 63;
    int w = threadIdx.x >> 6;
    if (blk < 33) {
        int task = blk * 4 + w;
        float al0 = attn_l[lane], al1 = attn_l[lane + 64];
        if (task < 128) {
            float part = W_src[task * DD + lane] * al0 +
                         W_src[task * DD + lane + 64] * al1;
            part = wave_sum(part);
            if (lane == 0) u[task] = part;
        } else if (task == 128) {
            float part = W_edge[lane] * al0 + W_edge[lane + 64] * al1;
            part = wave_sum(part);
            if (lane == 0) c_we[0] = part;
        }
    } else {
        int bm = (blk - 33) * 4 + w;     // < 512
        const float* h = h_dst + (size_t)bm * IN_DST;
        float a0 = 0.f, a1 = 0.f;
        #pragma unroll 8
        for (int k = 0; k < IN_DST; ++k) {
            float hk = h[k];
            a0 += hk * W_dst[k * DD + lane];
            a1 += hk * W_dst[k * DD + lane + 64];
        }
        feat_dst[(size_t)bm * DD + lane] = a0;
        feat_dst[(size_t)bm * DD + lane + 64] = a1;
        float r = a0 * attn_r[lane] + a1 * attn_r[lane + 64];
        r = wave_sum(r);
        if (lane == 0) er[bm] = r;
    }
}

// K2: per (b, o-tile), 1024 threads (16 waves -> 4 waves/SIMD). Stage H;
// el in-block (32-thread-group reduce); masked exp stats (M=0; logits
// bounded ~14, safe f32); partial contraction
// S_part[b,ti,m,i] = sum_o p[o,m]*H[o,i].
__global__ __launch_bounds__(1024) void ab_kernel(
    const float* __restrict__ edge_feat, const int* __restrict__ adj,
    const float* __restrict__ h_src, const float* __restrict__ u,
    const float* __restrict__ er, const float* __restrict__ c_we_p,
    float* __restrict__ S_part, float* __restrict__ zpart,
    float* __restrict__ separt) {
    __shared__ float H_l[TILE_O][HPAD];    // 16.9 KB
    __shared__ float P_l[TILE_O][N_MA];    // 8 KB
    __shared__ float u_l[DD];
    __shared__ float el_l[TILE_O];
    __shared__ float redz[16][64], redse[16][64];  // 8 KB

    int blk = blockIdx.x;               // 0..255
    int b = blk >> 5, ti = blk & 31;
    int o0 = ti * TILE_O;
    int nrows = min(TILE_O, N_OP - o0); // 32 (8 for ti==31)
    int t = threadIdx.x;                // 0..1023

    float cwe = c_we_p[0];

    // stage H tile: exactly 1024 float4 slots = 32 rows x 32 (coalesced)
    {
        int row = t >> 5, col = (t & 31) * 4;
        float4 hv = make_float4(0.f, 0.f, 0.f, 0.f);
        if (row < nrows)
            hv = *reinterpret_cast<const float4*>(
                h_src + ((size_t)(b * N_OP + o0 + row) * DD + col));
        *reinterpret_cast<float4*>(&H_l[row][col]) = hv;
    }
    if (t < DD) u_l[t] = u[t];
    __syncthreads();

    // el[r] = dot(H[r,:], u): 32 threads/row x 4 FMA (OOB rows give 0)
    {
        int r = t >> 5, sub = t & 31;
        float part = 0.f;
        #pragma unroll
        for (int q = 0; q < 4; ++q)
            part += H_l[r][sub + 32 * q] * u_l[sub + 32 * q];
        part += __shfl_xor(part, 1, 64);
        part += __shfl_xor(part, 2, 64);
        part += __shfl_xor(part, 4, 64);
        part += __shfl_xor(part, 8, 64);
        part += __shfl_xor(part, 16, 64);
        if (sub == 0) el_l[r] = part;
    }
    __syncthreads();

    // phase 1: p + per-tile stats (coalesced adj/ef rows); 16 row-groups
    int m = t & 63, og = t >> 6;        // og in [0,16)
    float er_bm = er[b * N_MA + m];
    float z = 0.f, se = 0.f;
    #pragma unroll
    for (int r = og; r < TILE_O; r += 16) {
        float p = 0.f;
        if (r < nrows) {
            size_t eidx = (size_t)(b * N_OP + o0 + r) * N_MA + m;
            if (adj[eidx]) {
                float efv = edge_feat[eidx];
                float v = lrelu(el_l[r] + er_bm + efv * cwe);
                p = __expf(v);
                z += p;
                se += p * efv;
            }
        }
        P_l[r][m] = p;
    }
    redz[og][m] = z;
    redse[og][m] = se;
    __syncthreads();

    if (t < 64) {
        float s = 0.f;
        #pragma unroll
        for (int g = 0; g < 16; ++g) s += redz[g][t];
        zpart[ti * 512 + b * N_MA + t] = s;
    } else if (t < 128) {
        int mm = t - 64;
        float s = 0.f;
        #pragma unroll
        for (int g = 0; g < 16; ++g) s += redse[g][mm];
        separt[ti * 512 + b * N_MA + mm] = s;
    }

    // phase 2: S_part[m][i] = sum_k P_l[k][m] * H_l[k][i]
    // thread (i4 = t&31, mg = t>>5 in [0,32)): i = i4*4..+3, m = mg*2..+1
    int i4 = t & 31, mg = t >> 5;
    float acc[2][4];
    #pragma unroll
    for (int a = 0; a < 2; ++a)
        #pragma unroll
        for (int c = 0; c < 4; ++c) acc[a][c] = 0.f;

    for (int k = 0; k < TILE_O; ++k) {
        float4 hv = *reinterpret_cast<const float4*>(&H_l[k][i4 * 4]);
        float2 pa = *reinterpret_cast<const float2*>(&P_l[k][mg * 2]);  // wave-broadcast
        float hh[4] = {hv.x, hv.y, hv.z, hv.w};
        #pragma unroll
        for (int ii = 0; ii < 4; ++ii) {
            acc[0][ii] += pa.x * hh[ii];
            acc[1][ii] += pa.y * hh[ii];
        }
    }

    #pragma unroll
    for (int mm = 0; mm < 2; ++mm) {
        size_t off = ((size_t)(b * NTILE + ti) * N_MA + mg * 2 + mm) * DD + i4 * 4;
        *reinterpret_cast<float4*>(S_part + off) =
            make_float4(acc[mm][0], acc[mm][1], acc[mm][2], acc[mm][3]);
    }
}

// K3: per (b,m), 256 threads: sum partials, matvec with W_src, epilogue
// sigmoid. (proven R11 kernel — 512 blocks already give 2 blocks/CU TLP)
__global__ __launch_bounds__(256) void c_kernel(
    const float* __restrict__ S_part, const float* __restrict__ zpart,
    const float* __restrict__ separt, const float* __restrict__ er,
    const float* __restrict__ feat_dst, const float* __restrict__ W_src,
    const float* __restrict__ W_edge, float* __restrict__ out) {
    __shared__ float Sp[2][DD];
    __shared__ float S_l[DD];
    __shared__ float Wp[2][DD];
    __shared__ float sZ, sSE;

    int bm = blockIdx.x;
    int b = bm >> 6, m = bm & 63;
    int t = threadIdx.x;
    int i = t & 127, h = t >> 7;
    int lane = t & 63, w = t >> 6;

    if (w == 0) {
        float v = (lane < NTILE) ? zpart[lane * 512 + bm] : 0.f;
        v = wave_sum(v);
        if (lane == 0) sZ = v;
    } else if (w == 1) {
        float v = (lane < NTILE) ? separt[lane * 512 + bm] : 0.f;
        v = wave_sum(v);
        if (lane == 0) sSE = v;
    }

    float ps = 0.f;
    #pragma unroll
    for (int q = 0; q < NTILE / 2; ++q) {
        int ti = h * (NTILE / 2) + q;
        ps += S_part[((size_t)(b * NTILE + ti) * N_MA + m) * DD + i];
    }
    Sp[h][i] = ps;
    __syncthreads();
    if (t < DD) S_l[t] = Sp[0][t] + Sp[1][t];
    __syncthreads();

    float acc = 0.f;
    #pragma unroll 8
    for (int q = 0; q < 64; ++q) {
        int ii = h * 64 + q;
        acc += S_l[ii] * W_src[ii * DD + i];
    }
    Wp[h][i] = acc;
    __syncthreads();

    if (t < DD) {
        float er_bm = er[bm];
        float p_kk = __expf(lrelu(2.f * er_bm));
        float Z = sZ + p_kk;
        float invZ = 1.f / Z;
        float bsrc = (Wp[0][i] + Wp[1][i]) * invZ;
        float val = W_edge[i] * (sSE * invZ) + bsrc +
                    feat_dst[(size_t)bm * DD + i] * (p_kk * invZ);
        out[(size_t)bm * DD + i] = 1.f / (1.f + __expf(-val));
    }
}

extern "C" void kernel_launch(void* const* d_in, const int* in_sizes, int n_in,
                              void* d_out, int out_size, void* d_ws, size_t ws_size,
                              hipStream_t stream) {
    const float* h_src = (const float*)d_in[0];
    const float* h_dst = (const float*)d_in[1];
    const float* edge_feat = (const float*)d_in[2];
    const int* adj = (const int*)d_in[3];
    const float* W_src = (const float*)d_in[4];
    const float* W_dst = (const float*)d_in[5];
    const float* W_edge = (const float*)d_in[6];
    const float* attn_l = (const float*)d_in[7];
    const float* attn_r = (const float*)d_in[8];
    float* out = (float*)d_out;

    float* ws = (float*)d_ws;
    float* u = ws;                     // 128
    float* c_we = ws + 128;            // 1
    float* er = ws + 8448;             // 512
    float* feat_dst = ws + 9216;       // 65536
    float* zpart = ws + 75008;         // 32*512 = 16384
    float* separt = ws + 91392;        // 16384
    float* S_part = ws + 107776;       // 8*32*64*128 = 2097152

    prep_fdst<<<161, 256, 0, stream>>>(W_src, W_edge, attn_l, h_dst, W_dst,
                                       attn_r, u, c_we, feat_dst, er);
    ab_kernel<<<NB * NTILE, 1024, 0, stream>>>(edge_feat, adj, h_src, u, er,
                                               c_we, S_part, zpart, separt);
    c_kernel<<<NB * N_MA, 256, 0, stream>>>(S_part, zpart, separt, er,
                                            feat_dst, W_src, W_edge, out);
}